// Round 9
// baseline (220.555 us; speedup 1.0000x reference)
//
#include <hip/hip_runtime.h>
#include <stdint.h>

typedef _Float16 f16x2 __attribute__((ext_vector_type(2)));
typedef _Float16 f16x8 __attribute__((ext_vector_type(8)));
typedef float f32x4 __attribute__((ext_vector_type(4)));

static __device__ __forceinline__ uint32_t perm(uint32_t hi, uint32_t lo, uint32_t sel) {
    return __builtin_amdgcn_perm(hi, lo, sel);
}
static __device__ __forceinline__ f16x2 bch2(uint32_t u) { union { uint32_t x; f16x2 h; } c; c.x = u; return c.h; }
static __device__ __forceinline__ uint32_t bcu(f16x2 h) { union { uint32_t x; f16x2 h; } c; c.h = h; return c.x; }
static __device__ __forceinline__ uint32_t pkrtz(float a, float b) {
    auto r = __builtin_amdgcn_cvt_pkrtz(a, b);
    union { decltype(r) h; uint32_t u; } c; c.h = r; return c.u;
}

#define NTOT 8192
#define KTOT 8192
#define SPLITS 8
#define KCHUNK 1024   // K per block: 8 periods of 128
#define BN 128        // N per block (8 waves x 16 rows)
#define PK 128        // k per staging period
#define NPER (KCHUNK / PK)

// out[m][n] = bias[n]  (atomic-fallback path only)
__global__ __launch_bounds__(256, 2) void nvfp4_init_out(const float* __restrict__ bias,
                                                         float* __restrict__ out) {
    int i = blockIdx.x * 256 + threadIdx.x;
    ((f32x4*)out)[i] = ((const f32x4*)bias)[i & 2047];
}

// out[m][n] = bias[n] + sum_s part[s][m][n]
__global__ __launch_bounds__(256, 2) void nvfp4_reduce(const float* __restrict__ part,
                                                       const float* __restrict__ bias,
                                                       float* __restrict__ out) {
    int i = blockIdx.x * 256 + threadIdx.x;
    f32x4 s = ((const f32x4*)bias)[i & 2047];
    #pragma unroll
    for (int p = 0; p < SPLITS; ++p) {
        f32x4 v = ((const f32x4*)part)[(size_t)p * 131072 + i];
        s = s + v;
    }
    ((f32x4*)out)[i] = s;
}

__global__ __launch_bounds__(512, 4) void nvfp4_gemm(const float* __restrict__ x,
                                                     const int* __restrict__ wp,
                                                     const float* __restrict__ wscale,
                                                     const float* __restrict__ gs,
                                                     float* __restrict__ dst,
                                                     int atomic_mode) {
    // LDS (~65 KiB => 2 blocks/CU):
    //  wl : compacted packed W, [buf][128 rows][16 u32], word-in-row XOR-swizzled.  2x8 KiB
    //  xtl: x as f16, [buf][64 rows][256 B], 16B-slot XOR-swizzled.                 2x16 KiB
    //  scl: scales as f16, [128 rows][66] (132 B row stride => conflict-free).      16.5 KiB
    __shared__ uint32_t wl[2][128 * 16];
    __shared__ __align__(16) uint8_t xtl[2][64 * 256];
    __shared__ uint16_t scl[128 * 66];

    const int tid = threadIdx.x;
    const int nb = blockIdx.x & 63;     // n-block 0..63
    const int ksp = blockIdx.x >> 6;    // k-split 0..7
    const int nbase = nb * BN;
    const int kc0 = ksp * KCHUNK;

    const int lane = tid & 63;
    const int wid = tid >> 6;     // 0..7
    const int l15 = lane & 15;
    const int grp = lane >> 4;    // 0..3

    // ---- staging maps ----
    // W: thread -> (row = (tid>>4) + i*32, 16B slot = tid&15); wave footprint: 4 rows x 256 contiguous B.
    const int wsrow = tid >> 4;         // 0..31
    const int wss = tid & 15;
    const int* wgp = wp + (size_t)(nbase + wsrow) * 4096 + (kc0 >> 1) + wss * 4;
    // x: thread -> (row = tid>>3, 4B col base = (tid&7)*4); wave footprint: 8 rows x 128 contiguous B.
    const int xsrow = tid >> 3;         // 0..63
    const int xss = tid & 7;
    const float* xgp = x + (size_t)xsrow * KTOT + kc0 + xss * 4;

    int4 wst[4];
    f32x4 xst[4];

    auto issueW = [&](int p) {
        #pragma unroll
        for (int i = 0; i < 4; ++i)
            wst[i] = *(const int4*)(wgp + (size_t)i * 32 * 4096 + p * 64);
    };
    auto issueX = [&](int p) {
        #pragma unroll
        for (int j = 0; j < 4; ++j)
            xst[j] = *(const f32x4*)(xgp + p * 128 + j * 32);
    };
    auto writeW = [&](int p) {
        uint32_t* wb = wl[p & 1];
        #pragma unroll
        for (int i = 0; i < 4; ++i) {
            int R = wsrow + i * 32;
            uint32_t v = (uint32_t)(wst[i].x & 0xff) | ((uint32_t)(wst[i].y & 0xff) << 8) |
                         ((uint32_t)(wst[i].z & 0xff) << 16) | ((uint32_t)wst[i].w << 24);
            wb[R * 16 + (wss ^ (R & 15))] = v;       // word-in-row swizzle
        }
    };
    auto writeX = [&](int p) {
        uint8_t* xb = xtl[p & 1];
        #pragma unroll
        for (int j = 0; j < 4; ++j) {
            uint32_t lo = pkrtz(xst[j].x, xst[j].y);
            uint32_t hi = pkrtz(xst[j].z, xst[j].w);
            int slot = j * 4 + (xss >> 1);
            uint32_t addr = (uint32_t)(xsrow * 256 + ((slot ^ (xsrow & 15)) << 4) + (xss & 1) * 8);
            uint2 dv; dv.x = lo; dv.y = hi;
            *(uint2*)(xb + addr) = dv;               // 16B-slot swizzle
        }
    };

    // ---- prologue: issue period 0, stage scales while loads fly, then write period 0 ----
    issueW(0);
    issueX(0);
    {
        float g = gs[0];
        float inv_g = (g != 0.0f) ? (1.0f / g) : 1.0f;
        int row = tid >> 2;              // 0..127
        int q = tid & 3;                 // 16-col quarter
        const float* sp = wscale + (size_t)(nbase + row) * 512 + (kc0 >> 4) + q * 16;
        #pragma unroll
        for (int j = 0; j < 4; ++j) {
            f32x4 v = *(const f32x4*)(sp + j * 4);
            uint32_t p01 = pkrtz(v.x * inv_g, v.y * inv_g);
            uint32_t p23 = pkrtz(v.z * inv_g, v.w * inv_g);
            uint32_t c = q * 16 + j * 4;
            *(uint32_t*)((uint8_t*)scl + row * 132 + c * 2) = p01;
            *(uint32_t*)((uint8_t*)scl + row * 132 + c * 2 + 4) = p23;
        }
    }
    writeW(0);
    writeX(0);
    __syncthreads();

    f32x4 acc[4];
    #pragma unroll
    for (int a = 0; a < 4; ++a)
        acc[a] = f32x4{0.f, 0.f, 0.f, 0.f};

    const uint32_t TH = 0x46444240u, TL = 0x3E3C3800u;  // f16 high-byte tables for e2m1 mags
    const int srowb = (wid * 16 + l15) * 132;
    const int wR = wid * 16 + l15;           // this lane's W row (R&15 == l15)

    for (int p = 0; p < NPER; ++p) {
        if (p + 1 < NPER) { issueW(p + 1); issueX(p + 1); }   // T14: issue early
        const uint32_t* wb = wl[p & 1];
        const uint8_t* xb = xtl[p & 1];

        #pragma unroll
        for (int tl = 0; tl < 4; ++tl) {
            // x fragments (swizzled b128)
            f16x8 af[4];
            #pragma unroll
            for (int mt = 0; mt < 4; ++mt) {
                int row = mt * 16 + l15;
                uint32_t addr = (uint32_t)(row * 256 + (((tl * 4 + grp) ^ l15) << 4));
                af[mt] = *(const f16x8*)(xb + addr);
            }
            // scale (f16, duplicated via perm)
            int scol = p * 8 + tl * 2 + (grp >> 1);
            uint32_t sr = *(const uint16_t*)((const uint8_t*)scl + srowb + scol * 2);
            f16x2 s2 = bch2(perm(0, sr, 0x01000100u));

            // W fragment: 4 B = 8 weights
            uint32_t b = wb[wR * 16 + ((tl * 4 + grp) ^ l15)];
            uint32_t sel_e = b & 0x07070707u;
            uint32_t sel_o = (b >> 4) & 0x07070707u;
            uint32_t he = perm(TH, TL, sel_e) | ((b & 0x08080808u) << 4);
            uint32_t ho = perm(TH, TL, sel_o) | (b & 0x80808080u);
            uint32_t d0 = perm(ho, he, 0x040C000Cu);
            uint32_t d1 = perm(ho, he, 0x050C010Cu);
            uint32_t d2 = perm(ho, he, 0x060C020Cu);
            uint32_t d3 = perm(ho, he, 0x070C030Cu);
            union { uint32_t u[4]; f16x8 h; } fr;
            fr.u[0] = bcu(bch2(d0) * s2);
            fr.u[1] = bcu(bch2(d1) * s2);
            fr.u[2] = bcu(bch2(d2) * s2);
            fr.u[3] = bcu(bch2(d3) * s2);
            #pragma unroll
            for (int mt = 0; mt < 4; ++mt)
                acc[mt] = __builtin_amdgcn_mfma_f32_16x16x32_f16(af[mt], fr.h, acc[mt], 0, 0, 0);
        }

        if (p + 1 < NPER) { writeW(p + 1); writeX(p + 1); }   // write late
        __syncthreads();
    }

    // ---- epilogue ----
    if (atomic_mode) {
        #pragma unroll
        for (int mt = 0; mt < 4; ++mt)
            #pragma unroll
            for (int q = 0; q < 4; ++q) {
                int row = mt * 16 + grp * 4 + q;
                int col = nbase + wid * 16 + l15;
                unsafeAtomicAdd(dst + (size_t)row * NTOT + col, acc[mt][q]);
            }
    } else {
        float* pd = dst + (size_t)ksp * 64 * NTOT;
        #pragma unroll
        for (int mt = 0; mt < 4; ++mt)
            #pragma unroll
            for (int q = 0; q < 4; ++q) {
                int row = mt * 16 + grp * 4 + q;
                int col = nbase + wid * 16 + l15;
                pd[(size_t)row * NTOT + col] = acc[mt][q];
            }
    }
}

extern "C" void kernel_launch(void* const* d_in, const int* in_sizes, int n_in,
                              void* d_out, int out_size, void* d_ws, size_t ws_size,
                              hipStream_t stream) {
    const float* x = (const float*)d_in[0];
    const int* wp = (const int*)d_in[1];
    const float* wscale = (const float*)d_in[2];
    const float* gs = (const float*)d_in[3];
    const float* bias = (const float*)d_in[4];
    float* out = (float*)d_out;

    const size_t need = (size_t)SPLITS * 64 * NTOT * sizeof(float);   // 16 MiB
    if (ws_size >= need) {
        nvfp4_gemm<<<dim3(SPLITS * (NTOT / BN)), dim3(512), 0, stream>>>(x, wp, wscale, gs, (float*)d_ws, 0);
        nvfp4_reduce<<<dim3(512), dim3(256), 0, stream>>>((const float*)d_ws, bias, out);
    } else {
        nvfp4_init_out<<<dim3(512), dim3(256), 0, stream>>>(bias, out);
        nvfp4_gemm<<<dim3(SPLITS * (NTOT / BN)), dim3(512), 0, stream>>>(x, wp, wscale, gs, out, 1);
    }
}

// Round 13
// 219.858 us; speedup vs baseline: 1.0032x; 1.0032x over previous
//
#include <hip/hip_runtime.h>
#include <stdint.h>

typedef _Float16 f16x2 __attribute__((ext_vector_type(2)));
typedef _Float16 f16x8 __attribute__((ext_vector_type(8)));
typedef float f32x4 __attribute__((ext_vector_type(4)));

static __device__ __forceinline__ uint32_t perm(uint32_t hi, uint32_t lo, uint32_t sel) {
    return __builtin_amdgcn_perm(hi, lo, sel);
}
static __device__ __forceinline__ f16x2 bch2(uint32_t u) { union { uint32_t x; f16x2 h; } c; c.x = u; return c.h; }
static __device__ __forceinline__ uint32_t bcu(f16x2 h) { union { uint32_t x; f16x2 h; } c; c.h = h; return c.x; }
static __device__ __forceinline__ uint32_t pkrtz(float a, float b) {
    auto r = __builtin_amdgcn_cvt_pkrtz(a, b);
    union { decltype(r) h; uint32_t u; } c; c.h = r; return c.u;
}

#define NTOT 8192
#define KTOT 8192
#define SPLITS 8
#define KCHUNK 1024   // K per block: 8 periods of 128
#define BN 128        // N per block (8 waves x 16 rows)
#define PK 128        // k per staging period
#define NPER (KCHUNK / PK)

// out[m][n] = bias[n]  (atomic-fallback path only)
__global__ __launch_bounds__(256, 2) void nvfp4_init_out(const float* __restrict__ bias,
                                                         float* __restrict__ out) {
    int i = blockIdx.x * 256 + threadIdx.x;
    ((f32x4*)out)[i] = ((const f32x4*)bias)[i & 2047];
}

// out[m][n] = bias[n] + sum_s part[s][m][n]
__global__ __launch_bounds__(256, 2) void nvfp4_reduce(const float* __restrict__ part,
                                                       const float* __restrict__ bias,
                                                       float* __restrict__ out) {
    int i = blockIdx.x * 256 + threadIdx.x;
    f32x4 s = ((const f32x4*)bias)[i & 2047];
    #pragma unroll
    for (int p = 0; p < SPLITS; ++p) {
        f32x4 v = ((const f32x4*)part)[(size_t)p * 131072 + i];
        s = s + v;
    }
    ((f32x4*)out)[i] = s;
}

__global__ __launch_bounds__(512, 4) void nvfp4_gemm(const float* __restrict__ x,
                                                     const int* __restrict__ wp,
                                                     const float* __restrict__ wscale,
                                                     const float* __restrict__ gs,
                                                     float* __restrict__ dst,
                                                     int atomic_mode) {
    // LDS (~65 KiB => 2 blocks/CU):
    //  wl : compacted packed W, [buf][128 rows][16 u32], word-in-row XOR-swizzled.  2x8 KiB
    //  xtl: x as f16, [buf][64 rows][256 B], 16B-slot XOR-swizzled.                 2x16 KiB
    //  scl: scales as f16, [128 rows][66] (132 B row stride => conflict-free).      16.5 KiB
    __shared__ uint32_t wl[2][128 * 16];
    __shared__ __align__(16) uint8_t xtl[2][64 * 256];
    __shared__ uint16_t scl[128 * 66];

    const int tid = threadIdx.x;
    const int nb = blockIdx.x & 63;     // n-block 0..63
    const int ksp = blockIdx.x >> 6;    // k-split 0..7
    const int nbase = nb * BN;
    const int kc0 = ksp * KCHUNK;

    const int lane = tid & 63;
    const int wid = tid >> 6;     // 0..7
    const int l15 = lane & 15;
    const int grp = lane >> 4;    // 0..3

    // ---- staging maps ----
    // W: thread -> (row = (tid>>4) + i*32, 16B slot = tid&15); wave footprint: 4 rows x 256 contiguous B.
    const int wsrow = tid >> 4;         // 0..31
    const int wss = tid & 15;
    const int* wgp = wp + (size_t)(nbase + wsrow) * 4096 + (kc0 >> 1) + wss * 4;
    // x: thread -> (row = tid>>3, 4B col base = (tid&7)*4); wave footprint: 8 rows x 128 contiguous B.
    const int xsrow = tid >> 3;         // 0..63
    const int xss = tid & 7;
    const float* xgp = x + (size_t)xsrow * KTOT + kc0 + xss * 4;

    // ---- depth-2 register pipeline: static A/B sets (no runtime indexing, rule 20) ----
    int4 wstA[4], wstB[4];
    f32x4 xstA[4], xstB[4];

    auto issueW = [&](int p, int4* wst) {
        #pragma unroll
        for (int i = 0; i < 4; ++i)
            wst[i] = *(const int4*)(wgp + (size_t)i * 32 * 4096 + p * 64);
    };
    auto issueX = [&](int p, f32x4* xst) {
        #pragma unroll
        for (int j = 0; j < 4; ++j)
            xst[j] = *(const f32x4*)(xgp + p * 128 + j * 32);
    };
    auto writeW = [&](int p, const int4* wst) {
        uint32_t* wb = wl[p & 1];
        #pragma unroll
        for (int i = 0; i < 4; ++i) {
            int R = wsrow + i * 32;
            uint32_t v = (uint32_t)(wst[i].x & 0xff) | ((uint32_t)(wst[i].y & 0xff) << 8) |
                         ((uint32_t)(wst[i].z & 0xff) << 16) | ((uint32_t)wst[i].w << 24);
            wb[R * 16 + (wss ^ (R & 15))] = v;       // word-in-row swizzle
        }
    };
    auto writeX = [&](int p, const f32x4* xst) {
        uint8_t* xb = xtl[p & 1];
        #pragma unroll
        for (int j = 0; j < 4; ++j) {
            uint32_t lo = pkrtz(xst[j].x, xst[j].y);
            uint32_t hi = pkrtz(xst[j].z, xst[j].w);
            int slot = j * 4 + (xss >> 1);
            uint32_t addr = (uint32_t)(xsrow * 256 + ((slot ^ (xsrow & 15)) << 4) + (xss & 1) * 8);
            uint2 dv; dv.x = lo; dv.y = hi;
            *(uint2*)(xb + addr) = dv;               // 16B-slot swizzle
        }
    };

    // ---- prologue ----
    // Load order matters for counted vmcnt: A(0) [oldest], scale-loads, B(1) [newest].
    // The scale-write then waits only to vmcnt(8) -> B's loads stay in flight across the barrier.
    issueW(0, wstA);
    issueX(0, xstA);
    const int srow_s = tid >> 2;              // 0..127
    const int sq = tid & 3;
    f32x4 sld[4];
    {
        const float* sp = wscale + (size_t)(nbase + srow_s) * 512 + (kc0 >> 4) + sq * 16;
        #pragma unroll
        for (int j = 0; j < 4; ++j)
            sld[j] = *(const f32x4*)(sp + j * 4);
    }
    issueW(1, wstB);
    issueX(1, xstB);
    {
        float g = gs[0];
        float inv_g = (g != 0.0f) ? (1.0f / g) : 1.0f;
        #pragma unroll
        for (int j = 0; j < 4; ++j) {
            uint32_t p01 = pkrtz(sld[j].x * inv_g, sld[j].y * inv_g);
            uint32_t p23 = pkrtz(sld[j].z * inv_g, sld[j].w * inv_g);
            uint32_t c = sq * 16 + j * 4;
            *(uint32_t*)((uint8_t*)scl + srow_s * 132 + c * 2) = p01;
            *(uint32_t*)((uint8_t*)scl + srow_s * 132 + c * 2 + 4) = p23;
        }
    }
    writeW(0, wstA);
    writeX(0, xstA);
    // raw barrier: LDS visibility only (lgkmcnt), global->reg loads stay outstanding
    asm volatile("s_waitcnt lgkmcnt(0)\n\ts_barrier" ::: "memory");

    f32x4 acc[4];
    #pragma unroll
    for (int a = 0; a < 4; ++a)
        acc[a] = f32x4{0.f, 0.f, 0.f, 0.f};

    const uint32_t TH = 0x46444240u, TL = 0x3E3C3800u;  // f16 high-byte tables for e2m1 mags
    const int srowb = (wid * 16 + l15) * 132;
    const int wR = wid * 16 + l15;           // this lane's W row (R&15 == l15)

    #pragma unroll
    for (int p = 0; p < NPER; ++p) {
        // issue period p+2 into the register set freed by write(p+1) of the PREVIOUS iter
        if (p + 2 < NPER) {
            if ((p & 1) == 0) { issueW(p + 2, wstA); issueX(p + 2, xstA); }
            else              { issueW(p + 2, wstB); issueX(p + 2, xstB); }
        }
        const uint32_t* wb = wl[p & 1];
        const uint8_t* xb = xtl[p & 1];

        #pragma unroll
        for (int tl = 0; tl < 4; ++tl) {
            // x fragments (swizzled b128)
            f16x8 af[4];
            #pragma unroll
            for (int mt = 0; mt < 4; ++mt) {
                int row = mt * 16 + l15;
                uint32_t addr = (uint32_t)(row * 256 + (((tl * 4 + grp) ^ l15) << 4));
                af[mt] = *(const f16x8*)(xb + addr);
            }
            // scale (f16, duplicated via perm)
            int scol = p * 8 + tl * 2 + (grp >> 1);
            uint32_t sr = *(const uint16_t*)((const uint8_t*)scl + srowb + scol * 2);
            f16x2 s2 = bch2(perm(0, sr, 0x01000100u));

            // W fragment: 4 B = 8 weights
            uint32_t b = wb[wR * 16 + ((tl * 4 + grp) ^ l15)];
            uint32_t sel_e = b & 0x07070707u;
            uint32_t sel_o = (b >> 4) & 0x07070707u;
            uint32_t he = perm(TH, TL, sel_e) | ((b & 0x08080808u) << 4);
            uint32_t ho = perm(TH, TL, sel_o) | (b & 0x80808080u);
            uint32_t d0 = perm(ho, he, 0x040C000Cu);
            uint32_t d1 = perm(ho, he, 0x050C010Cu);
            uint32_t d2 = perm(ho, he, 0x060C020Cu);
            uint32_t d3 = perm(ho, he, 0x070C030Cu);
            union { uint32_t u[4]; f16x8 h; } fr;
            fr.u[0] = bcu(bch2(d0) * s2);
            fr.u[1] = bcu(bch2(d1) * s2);
            fr.u[2] = bcu(bch2(d2) * s2);
            fr.u[3] = bcu(bch2(d3) * s2);
            #pragma unroll
            for (int mt = 0; mt < 4; ++mt)
                acc[mt] = __builtin_amdgcn_mfma_f32_16x16x32_f16(af[mt], fr.h, acc[mt], 0, 0, 0);
        }

        if (p + 1 < NPER) {
            // write(p+1): compiler emits a COUNTED vmcnt here (p+2's 8 loads remain in flight)
            if ((p & 1) == 0) { writeW(p + 1, wstB); writeX(p + 1, xstB); }
            else              { writeW(p + 1, wstA); writeX(p + 1, xstA); }
            asm volatile("s_waitcnt lgkmcnt(0)\n\ts_barrier" ::: "memory");
        }
    }

    // ---- epilogue ----
    if (atomic_mode) {
        #pragma unroll
        for (int mt = 0; mt < 4; ++mt)
            #pragma unroll
            for (int q = 0; q < 4; ++q) {
                int row = mt * 16 + grp * 4 + q;
                int col = nbase + wid * 16 + l15;
                unsafeAtomicAdd(dst + (size_t)row * NTOT + col, acc[mt][q]);
            }
    } else {
        float* pd = dst + (size_t)ksp * 64 * NTOT;
        #pragma unroll
        for (int mt = 0; mt < 4; ++mt)
            #pragma unroll
            for (int q = 0; q < 4; ++q) {
                int row = mt * 16 + grp * 4 + q;
                int col = nbase + wid * 16 + l15;
                pd[(size_t)row * NTOT + col] = acc[mt][q];
            }
    }
}

extern "C" void kernel_launch(void* const* d_in, const int* in_sizes, int n_in,
                              void* d_out, int out_size, void* d_ws, size_t ws_size,
                              hipStream_t stream) {
    const float* x = (const float*)d_in[0];
    const int* wp = (const int*)d_in[1];
    const float* wscale = (const float*)d_in[2];
    const float* gs = (const float*)d_in[3];
    const float* bias = (const float*)d_in[4];
    float* out = (float*)d_out;

    const size_t need = (size_t)SPLITS * 64 * NTOT * sizeof(float);   // 16 MiB
    if (ws_size >= need) {
        nvfp4_gemm<<<dim3(SPLITS * (NTOT / BN)), dim3(512), 0, stream>>>(x, wp, wscale, gs, (float*)d_ws, 0);
        nvfp4_reduce<<<dim3(512), dim3(256), 0, stream>>>((const float*)d_ws, bias, out);
    } else {
        nvfp4_init_out<<<dim3(512), dim3(256), 0, stream>>>(bias, out);
        nvfp4_gemm<<<dim3(SPLITS * (NTOT / BN)), dim3(512), 0, stream>>>(x, wp, wscale, gs, out, 1);
    }
}